// Round 10
// baseline (1334.354 us; speedup 1.0000x reference)
//
#include <hip/hip_runtime.h>
#include <stdint.h>

#define B_ 16
#define S_ 2048
#define F_ 129
#define H_ 128
#define G_ 512   // 4*H

typedef float f32x4 __attribute__((ext_vector_type(4)));
typedef float f32x4a4 __attribute__((ext_vector_type(4), aligned(4)));
typedef short s16x8 __attribute__((ext_vector_type(8)));
typedef _Float16 f16x8 __attribute__((ext_vector_type(8)));
typedef _Float16 f16x4 __attribute__((ext_vector_type(4)));

// LDS-only barrier: waits ds ops, does NOT drain vmcnt.
#define BAR_LDS() __asm__ volatile("s_waitcnt lgkmcnt(0)\n\ts_barrier" ::: "memory")

#define L2E 1.44269504088896f

__device__ inline unsigned short h2bits(_Float16 h) {
  union { _Float16 h; unsigned short u; } v; v.h = h; return v.u;
}
__device__ inline unsigned short f2h(float f) { return h2bits((_Float16)f); }
__device__ inline float rcp_(float x) { return __builtin_amdgcn_rcpf(x); }
__device__ inline float exp2_(float x) {
  float r; __asm__("v_exp_f32 %0, %1" : "=v"(r) : "v"(x)); return r;
}

// tid0 spins with RELAXED agent loads (no L2-invalidate storm; R7/R8 lesson),
// then ONE acquire load for the synchronizes-with edge. Deadline-bounded.
__device__ inline void wait_flag(int* f, int tgt, int tid, long deadline) {
  if (tid == 0) {
    if (__hip_atomic_load(f, __ATOMIC_RELAXED, __HIP_MEMORY_SCOPE_AGENT) < tgt) {
      while (__hip_atomic_load(f, __ATOMIC_RELAXED, __HIP_MEMORY_SCOPE_AGENT) < tgt) {
        __builtin_amdgcn_s_sleep(32);
        if ((long)__builtin_amdgcn_s_memrealtime() > deadline) break;
      }
    }
    (void)__hip_atomic_load(f, __ATOMIC_ACQUIRE, __HIP_MEMORY_SCOPE_AGENT);
  }
  __syncthreads();
}

// ---------------------------------------------------------------------------
// front_kernel round 23 = R3's proven front (943us: lstm blocks 0-3 + xg
// 4-515 chunk-major + rbf 516-1027, xgprog flag protocol) + ONE change:
// the lstm ALSO stores h transposed to qbfT[b][u][t] (1 extra fire-and-forget
// scalar store/step; consecutive t hit the same L2 line). This makes the
// attention V-transpose free (see back_kernel). Mega-fusion branch (R17-R22)
// closed: steady 1143-1163us vs this split's 1131 -- the all-CU coexistence
// stretches the scan window ~200us regardless of prefetch depth (DVFS/fabric
// suspected), eating the entire fusion benefit.
// ---------------------------------------------------------------------------
__global__ __launch_bounds__(512, 2) void front_kernel(
    const float* __restrict__ x, const float* __restrict__ prot,
    const float* __restrict__ W_ih, const float* __restrict__ W_hh,
    const float* __restrict__ b_ih, const float* __restrict__ b_hh,
    _Float16* __restrict__ xg, unsigned short* __restrict__ qbf,
    unsigned short* __restrict__ qbfT, float* __restrict__ kf,
    int* __restrict__ prog) {
  // >160KiB/2: exactly 1 block/CU everywhere (isolates lstm CUs).
  __shared__ __align__(16) char smem[82048];
  int tid = threadIdx.x;
  int blk = blockIdx.x;
  long deadline = (long)__builtin_amdgcn_s_memrealtime() + 4000000L;

  if (blk < 4) {
    // ------------------------- LSTM scan -------------------------
    _Float16 (*hbuf)[4 * 144] = (_Float16 (*)[4 * 144])smem;
    int w = tid >> 6, lane = tid & 63;
    int n16 = lane & 15;
    int q8 = lane >> 4;
    int ab = n16 >> 2;
    int u = (w << 4) | n16;
    int bb = blk * 4;
    f16x8 Wf[4][4];
    #pragma unroll
    for (int ty = 0; ty < 4; ++ty) {
      float gs = (ty == 2) ? (2.f * L2E) : (-L2E);
      #pragma unroll
      for (int kb = 0; kb < 4; ++kb) {
        const float* src = &W_hh[(ty * 128 + u) * H_ + kb * 32 + q8 * 8];
        f16x8 v;
        #pragma unroll
        for (int j = 0; j < 8; ++j) v[j] = (_Float16)(src[j] * gs);
        Wf[ty][kb] = v;
      }
    }
    for (int i = tid; i < 2 * 4 * 144; i += 512)
      ((_Float16*)hbuf)[i] = (_Float16)0.f;
    float c = 0.f;
    int hoff = ab * 144 + q8 * 8;
    const _Float16* h0 = &hbuf[0][hoff];
    const _Float16* h1 = &hbuf[1][hoff];
    _Float16* hw = &hbuf[0][q8 * 144 + u];
    const int hstride = 4 * 144;
    const _Float16* xb = xg + (long)(bb + q8) * S_ * G_ + u * 4;
    unsigned short* qp = qbf + (long)(bb + q8) * S_ * H_ + u - H_;
    unsigned short* qpT = qbfT + ((long)(bb + q8) * H_ + u) * S_ - 1;
    const _Float16* xpf = xb + 4 * G_;
    // wait for xg chunks 0,1 (covers preload + first group's prefetch)
    wait_flag(&prog[0], 16, tid, deadline);
    wait_flag(&prog[1], 16, tid, deadline);
    f16x4 cur[4];
    #pragma unroll
    for (int p = 0; p < 4; ++p) cur[p] = *(const f16x4*)(xb + (long)p * G_);
    unsigned short hvp = 0;
    __syncthreads();
    for (int t = 0; t < S_; t += 4) {
      if ((t & 63) == 0 && t != 0 && t < 1984)
        wait_flag(&prog[(t >> 6) + 1], 16, tid, deadline);
      #pragma unroll
      for (int p = 0; p < 4; ++p) {
        BAR_LDS();
        const _Float16* hsrc = (p & 1) ? h0 : h1;
        f16x8 A[4];
        #pragma unroll
        for (int kb = 0; kb < 4; ++kb)
          A[kb] = *(const f16x8*)(hsrc + kb * 32);
        if (t + p > 0) {
          *qp = hvp;
          *qpT = hvp;
        }
        qp += H_;
        qpT += 1;
        f16x4 xcur = cur[p];
        cur[p] = *(const f16x4*)xpf;
        xpf += G_;
        f32x4 r0a[4], r1a[4];
        #pragma unroll
        for (int ty = 0; ty < 4; ++ty) {
          f32x4 a0, a1;
          a0[0] = (float)xcur[ty]; a0[1] = 0.f; a0[2] = 0.f; a0[3] = 0.f;
          a1[0] = 0.f; a1[1] = 0.f; a1[2] = 0.f; a1[3] = 0.f;
          a0 = __builtin_amdgcn_mfma_f32_16x16x32_f16(A[0], Wf[ty][0], a0, 0, 0, 0);
          a1 = __builtin_amdgcn_mfma_f32_16x16x32_f16(A[2], Wf[ty][2], a1, 0, 0, 0);
          a0 = __builtin_amdgcn_mfma_f32_16x16x32_f16(A[1], Wf[ty][1], a0, 0, 0, 0);
          a1 = __builtin_amdgcn_mfma_f32_16x16x32_f16(A[3], Wf[ty][3], a1, 0, 0, 0);
          r0a[ty] = a0; r1a[ty] = a1;
        }
        float g0 = r0a[0][0] + r1a[0][0];
        float g1 = r0a[1][0] + r1a[1][0];
        float g2 = r0a[2][0] + r1a[2][0];
        float g3 = r0a[3][0] + r1a[3][0];
        // pre-scaled: g0,g1,g3 by -log2e; g2 by 2log2e
        float ai = rcp_(1.f + exp2_(g0));
        float af = rcp_(1.f + exp2_(g1));
        float ag = 1.f - 2.f * rcp_(1.f + exp2_(g2));
        float ao = rcp_(1.f + exp2_(g3));
        c = af * c + ai * ag;
        float th = 1.f - 2.f * rcp_(1.f + exp2_(c * (2.f * L2E)));
        float hv = ao * th;
        _Float16 hf = (_Float16)hv;
        hw[(p & 1) * hstride] = hf;
        hvp = h2bits(hf);
      }
    }
    *qp = hvp;
    *qpT = hvp;

  } else if (blk < 516) {
    // ------------------------- xg GEMM -------------------------
    _Float16 (*xs)[136] = (_Float16 (*)[136])smem;             // 64x136
    _Float16 (*ws)[136] = (_Float16 (*)[136])(smem + 17408);   // 128x136
    float* bsum = (float*)(smem + 17408 + 34816);              // 512 f32
    int xblk = blk - 4;
    int batch = xblk & 15, chunk = xblk >> 4;                  // chunk-major
    long R0 = (long)batch * S_ + chunk * 64;
    int lane = tid & 63, w = tid >> 6;
    int tw = w & 3, hi = w >> 2;
    int l15 = lane & 15, q = lane >> 4;
    for (int it = 0; it < 4; ++it) {
      int i = tid + it * 512;          // 2048 = 64 rows * 32 quads
      int r = i >> 5, cx = (i & 31) * 4;
      f32x4a4 v = *(const f32x4a4*)&x[(R0 + r) * 129 + cx];
      f16x4 hq;
      #pragma unroll
      for (int j = 0; j < 4; ++j) hq[j] = (_Float16)v[j];
      *(f16x4*)&xs[r][cx] = hq;
    }
    if (tid < 64) xs[tid][128] = (_Float16)x[(R0 + tid) * 129 + 128];
    bsum[tid] = b_ih[tid] + b_hh[tid];
    __syncthreads();
    f16x8 Bf[4];
    #pragma unroll
    for (int kb = 0; kb < 4; ++kb)
      Bf[kb] = *(const f16x8*)&xs[16 * tw + l15][kb * 32 + q * 8];
    float x128 = (float)xs[16 * tw + l15][128];
    f16x4 res[16];                     // [t*4+r], element = gate chunk
    #pragma unroll
    for (int cg = 0; cg < 4; ++cg) {
      __syncthreads();                 // prior chunk's A-reads done
      for (int it = 0; it < 8; ++it) {
        int i = tid + it * 512;        // 4096 = 128 rows * 32 quads
        int r = i >> 5, cc = (i & 31) * 4;
        f32x4a4 v = *(const f32x4a4*)&W_ih[(long)(cg * 128 + r) * 129 + cc];
        f16x4 hq;
        #pragma unroll
        for (int j = 0; j < 4; ++j) hq[j] = (_Float16)v[j];
        *(f16x4*)&ws[r][cc] = hq;
      }
      if (tid < 128) ws[tid][128] = (_Float16)W_ih[(long)(cg * 128 + tid) * 129 + 128];
      __syncthreads();
      float gs = (cg == 2) ? (2.f * L2E) : (-L2E);
      #pragma unroll
      for (int t = 0; t < 4; ++t) {    // waves split t-tiles: hi*4+t
        int tt = hi * 4 + t;
        f32x4 acc;
        acc[0] = 0.f; acc[1] = 0.f; acc[2] = 0.f; acc[3] = 0.f;
        #pragma unroll
        for (int kb = 0; kb < 4; ++kb) {
          f16x8 Af = *(const f16x8*)&ws[tt * 16 + l15][kb * 32 + q * 8];
          acc = __builtin_amdgcn_mfma_f32_16x16x32_f16(Af, Bf[kb], acc, 0, 0, 0);
        }
        #pragma unroll
        for (int r = 0; r < 4; ++r) {
          int unit = tt * 16 + q * 4 + r;
          float vv = (acc[r] + bsum[cg * 128 + unit] + x128 * (float)ws[unit][128]) * gs;
          res[t * 4 + r][cg] = (_Float16)vv;
        }
      }
    }
    long rowbase = (R0 + 16 * tw + l15) * G_;
    #pragma unroll
    for (int t = 0; t < 4; ++t)
      #pragma unroll
      for (int r = 0; r < 4; ++r)
        *(f16x4*)&xg[rowbase + ((hi * 4 + t) * 16 + q * 4 + r) * 4] = res[t * 4 + r];
    __syncthreads();                   // drains each wave's vmcnt before barrier
    if (tid == 0) {
      __threadfence();
      __hip_atomic_fetch_add(&prog[chunk], 1, __ATOMIC_RELEASE, __HIP_MEMORY_SCOPE_AGENT);
    }

  } else {
    // ------------------------- RBF -------------------------
    int rblk = blk - 516;
    int wave = tid >> 6, lane = tid & 63;
    for (int it = 0; it < 8; ++it) {
      long row = (long)rblk * 64 + it * 8 + wave;
      const float* xr = x + row * F_;
      const float* pr = prot + row * F_;
      float ss = 0.f;
      for (int k = lane; k < F_; k += 64) { float d = xr[k] - pr[k]; ss += d * d; }
      #pragma unroll
      for (int off = 32; off; off >>= 1) ss += __shfl_xor(ss, off, 64);
      if (lane == 0) kf[row] = __expf(-ss);
    }
  }
}

// ---------------------------------------------------------------------------
// back_kernel round 23 = R3's proven back (attn+mlp fused, 185us) + V staged
// from qbfT with 4 coalesced b128 load/store pairs per thread per chunk --
// replaces the 32 scalar LDS transpose stores (+addr math). Same XOR-swizzled
// VT layout, so the PV read path is byte-identical. LDS overlay unchanged:
// hb[2][64][136] (34816B); Ps (9216B) inside hb[1] (attn-phase only);
// Ks+VT (35840B) / wl+bl (39744B) share the tail region. 74560B -> 2/CU.
// ---------------------------------------------------------------------------
__global__ __launch_bounds__(256) void back_kernel(
    const unsigned short* __restrict__ qbf, const unsigned short* __restrict__ qbfT,
    const float* __restrict__ kf,
    const float* __restrict__ Wc, const float* __restrict__ bc,
    const float* __restrict__ Wh, const float* __restrict__ bh,
    float* __restrict__ out) {
  __shared__ __align__(16) char smem[74560];
  _Float16 (*hb)[64][136] = (_Float16 (*)[64][136])smem;            // 2x17408
  unsigned short* Ps = (unsigned short*)(smem + 17408);             // in hb[1]
  unsigned short* Ks = (unsigned short*)(smem + 34816);             // 17408
  unsigned short* VT = (unsigned short*)(smem + 34816 + 17408);     // 18432
  _Float16 (*wl)[136] = (_Float16 (*)[136])(smem + 34816);         // 39168
  float* bl = (float*)(smem + 34816 + 39168);                       // 576

  int tid = threadIdx.x;
  int lane = tid & 63, w = tid >> 6;
  int b = blockIdx.x >> 5;
  int q0 = (blockIdx.x & 31) * 64;
  long R0 = (long)blockIdx.x * 64;     // == b*S + q0
  const unsigned short* qb = qbf + (long)b * S_ * H_;
  const unsigned short* qbT = qbfT + (long)b * H_ * S_;
  int l15 = lane & 15;
  int q = lane >> 4;
  int koff = q * 8;

  // ---- attention phase ----
  f16x8 qfrag[4];
  #pragma unroll
  for (int kb = 0; kb < 4; ++kb)
    qfrag[kb] = *(const f16x8*)(qb + (long)(q0 + w * 16 + l15) * H_ + kb * 32 + koff);
  f32x4 oacc[8];
  #pragma unroll
  for (int n = 0; n < 8; ++n)
    #pragma unroll
    for (int r = 0; r < 4; ++r) oacc[n][r] = 0.f;
  float mrow[4], lrow[4];
  #pragma unroll
  for (int r = 0; r < 4; ++r) { mrow[r] = -1e30f; lrow[r] = 0.f; }
  const float scale = 0.08804509063256238f;  // 1/sqrt(129)
  unsigned short* Pw = Ps + w * 16 * 72;
  for (int t = 0; t < S_ / 64; ++t) {
    {
      // K: row-major from qbf (unchanged)
      int rr = tid >> 4;
      int c0 = (tid & 15) * 8;
      #pragma unroll
      for (int pch = 0; pch < 4; ++pch) {
        int r = pch * 16 + rr;
        *(s16x8*)(&Ks[r * 136 + c0]) =
            *(const s16x8*)(qb + (long)(t * 64 + r) * H_ + c0);
      }
      // V: unit-major from qbfT -- b128 coalesced, swizzled VT rows.
      #pragma unroll
      for (int vt = 0; vt < 4; ++vt) {
        int idx = tid + vt * 256;      // 1024 = 128 d * 8 tgroups
        int d = idx >> 3, tg = idx & 7;
        s16x8 v = *(const s16x8*)(qbT + (long)d * S_ + t * 64 + tg * 8);
        *(s16x8*)(&VT[d * 72 + ((tg ^ ((d >> 3) & 7)) << 3)]) = v;
      }
    }
    __syncthreads();
    f32x4 sacc[4];
    #pragma unroll
    for (int n = 0; n < 4; ++n) {
      f32x4 acc;
      #pragma unroll
      for (int r = 0; r < 4; ++r) acc[r] = 0.f;
      #pragma unroll
      for (int kb = 0; kb < 4; ++kb) {
        f16x8 bfrag = *(const f16x8*)(&Ks[(n * 16 + l15) * 136 + kb * 32 + koff]);
        acc = __builtin_amdgcn_mfma_f32_16x16x32_f16(qfrag[kb], bfrag, acc, 0, 0, 0);
      }
      sacc[n] = acc;
    }
    #pragma unroll
    for (int r = 0; r < 4; ++r) {
      float mx = fmaxf(fmaxf(sacc[0][r], sacc[1][r]), fmaxf(sacc[2][r], sacc[3][r]));
      #pragma unroll
      for (int m = 1; m < 16; m <<= 1) mx = fmaxf(mx, __shfl_xor(mx, m, 64));
      mx *= scale;
      float mnew = fmaxf(mrow[r], mx);
      float alpha = __expf(mrow[r] - mnew);
      mrow[r] = mnew;
      float psum = 0.f;
      #pragma unroll
      for (int n = 0; n < 4; ++n) {
        float pv = __expf(sacc[n][r] * scale - mnew);
        sacc[n][r] = pv;
        psum += pv;
      }
      #pragma unroll
      for (int m = 1; m < 16; m <<= 1) psum += __shfl_xor(psum, m, 64);
      lrow[r] = lrow[r] * alpha + psum;
      #pragma unroll
      for (int n = 0; n < 8; ++n) oacc[n][r] *= alpha;
    }
    #pragma unroll
    for (int n = 0; n < 4; ++n)
      #pragma unroll
      for (int r = 0; r < 4; ++r)
        Pw[(q * 4 + r) * 72 + n * 16 + l15] = f2h(sacc[n][r]);
    __syncthreads();
    #pragma unroll
    for (int kb = 0; kb < 2; ++kb) {
      f16x8 afrag = *(const f16x8*)(&Pw[l15 * 72 + kb * 32 + koff]);
      #pragma unroll
      for (int n = 0; n < 8; ++n) {
        int d = n * 16 + l15;
        int rb = ((kb * 32 + koff) >> 3) ^ ((d >> 3) & 7);
        f16x8 bfrag = *(const f16x8*)(&VT[d * 72 + (rb << 3)]);
        oacc[n] = __builtin_amdgcn_mfma_f32_16x16x32_f16(afrag, bfrag, oacc[n], 0, 0, 0);
      }
    }
    __syncthreads();
  }
  // ---- epilogue: oacc -> hb[0] (f16), kf -> col 128 ----
  float rl4[4];
  #pragma unroll
  for (int r = 0; r < 4; ++r) rl4[r] = rcp_(lrow[r]);
  #pragma unroll
  for (int n = 0; n < 8; ++n)
    #pragma unroll
    for (int r = 0; r < 4; ++r)
      hb[0][w * 16 + q * 4 + r][n * 16 + l15] = (_Float16)(oacc[n][r] * rl4[r]);
  if (tid < 64) hb[0][tid][128] = (_Float16)kf[R0 + tid];

  // ---- MLP phase ----
  int cur = 0;
  for (int l = 0; l < 4; ++l) {
    __syncthreads();                 // h writes + prior wl reads done
    for (int it = 0; it < 18; ++it) {
      int i = tid + it * 256;        // 4608 = 144 rows * 32 quads
      int r = i >> 5, cc = (i & 31) * 4;
      int rs = (r < 129) ? r : 128;  // dup row 128 into pad rows (garbage-safe)
      f32x4a4 v = *(const f32x4a4*)&Wc[((long)l * 129 + rs) * 129 + cc];
      f16x4 hq;
      #pragma unroll
      for (int j = 0; j < 4; ++j) hq[j] = (_Float16)v[j];
      *(f16x4*)&wl[r][cc] = hq;
    }
    if (tid < 144) {
      int rs = (tid < 129) ? tid : 128;
      wl[tid][128] = (_Float16)Wc[((long)l * 129 + rs) * 129 + 128];
      bl[tid] = bc[l * 129 + rs];
    }
    __syncthreads();
    f16x8 Bf[4];
    #pragma unroll
    for (int kb = 0; kb < 4; ++kb)
      Bf[kb] = *(const f16x8*)&hb[cur][16 * w + l15][kb * 32 + q * 8];
    float h128 = (float)hb[cur][16 * w + l15][128];
    int nxt = cur ^ 1;
    #pragma unroll
    for (int t = 0; t < 9; ++t) {
      f32x4 acc;
      acc[0] = 0.f; acc[1] = 0.f; acc[2] = 0.f; acc[3] = 0.f;
      #pragma unroll
      for (int kb = 0; kb < 4; ++kb) {
        f16x8 Af = *(const f16x8*)&wl[t * 16 + l15][kb * 32 + q * 8];
        acc = __builtin_amdgcn_mfma_f32_16x16x32_f16(Af, Bf[kb], acc, 0, 0, 0);
      }
      f16x4 hv;
      #pragma unroll
      for (int r = 0; r < 4; ++r) {
        int u = t * 16 + q * 4 + r;
        float v = acc[r] + bl[u] + h128 * (float)wl[u][128];
        hv[r] = (_Float16)fmaxf(v, 0.f);
      }
      if (t < 8)
        *(f16x4*)&hb[nxt][16 * w + l15][t * 16 + q * 4] = hv;
      else if (q == 0)
        hb[nxt][16 * w + l15][128] = hv[0];   // only unit 128 is real
    }
    cur ^= 1;
  }
  __syncthreads();
  if (tid < 128) {
    int row = tid >> 1, j = tid & 1;
    float z = bh[j];
    const float* whp = Wh + j * 129;
    for (int k = 0; k < 129; ++k) z += (float)hb[cur][row][k] * whp[k];
    float zo = __shfl_xor(z, 1, 64);   // partner lane: same row, other class
    float mx = fmaxf(z, zo);
    float lse = mx + __logf(__expf(z - mx) + __expf(zo - mx));
    out[(R0 + row) * 2 + j] = z - lse;
  }
}

extern "C" void kernel_launch(void* const* d_in, const int* in_sizes, int n_in,
                              void* d_out, int out_size, void* d_ws, size_t ws_size,
                              hipStream_t stream) {
  const float* x    = (const float*)d_in[0];
  const float* prot = (const float*)d_in[1];
  const float* W_ih = (const float*)d_in[2];
  const float* W_hh = (const float*)d_in[3];
  const float* b_ih = (const float*)d_in[4];
  const float* b_hh = (const float*)d_in[5];
  const float* Wc   = (const float*)d_in[6];
  const float* bc   = (const float*)d_in[7];
  const float* Wh   = (const float*)d_in[8];
  const float* bh   = (const float*)d_in[9];
  float* out = (float*)d_out;
  char* ws = (char*)d_ws;
  _Float16* xgh        = (_Float16*)(ws);                      // 33554432 B
  unsigned short* qbf  = (unsigned short*)(ws + 33554432);     //  8388608 B (f16 bits, [b][t][u])
  unsigned short* qbfT = (unsigned short*)(ws + 41943040);     //  8388608 B (f16 bits, [b][u][t])
  float* kf            = (float*)(ws + 50331648);              //   131072 B
  int* prog            = (int*)(ws + 50462720);                //      128 B

  hipMemsetAsync(prog, 0, 128, stream);
  hipLaunchKernelGGL(front_kernel, dim3(1028), dim3(512), 0, stream,
                     x, prot, W_ih, W_hh, b_ih, b_hh, xgh, qbf, qbfT, kf, prog);
  hipLaunchKernelGGL(back_kernel, dim3(512), dim3(256), 0, stream,
                     qbf, qbfT, kf, Wc, bc, Wh, bh, out);
}

// Round 11
// 1120.502 us; speedup vs baseline: 1.1909x; 1.1909x over previous
//
#include <hip/hip_runtime.h>
#include <stdint.h>

#define B_ 16
#define S_ 2048
#define F_ 129
#define H_ 128
#define G_ 512   // 4*H

typedef float f32x4 __attribute__((ext_vector_type(4)));
typedef float f32x4a4 __attribute__((ext_vector_type(4), aligned(4)));
typedef short s16x8 __attribute__((ext_vector_type(8)));
typedef _Float16 f16x8 __attribute__((ext_vector_type(8)));
typedef _Float16 f16x4 __attribute__((ext_vector_type(4)));

// LDS-only barrier: waits ds ops, does NOT drain vmcnt.
#define BAR_LDS() __asm__ volatile("s_waitcnt lgkmcnt(0)\n\ts_barrier" ::: "memory")

#define L2E 1.44269504088896f

__device__ inline unsigned short h2bits(_Float16 h) {
  union { _Float16 h; unsigned short u; } v; v.h = h; return v.u;
}
__device__ inline unsigned short f2h(float f) { return h2bits((_Float16)f); }
__device__ inline float rcp_(float x) { return __builtin_amdgcn_rcpf(x); }
__device__ inline float exp2_(float x) {
  float r; __asm__("v_exp_f32 %0, %1" : "=v"(r) : "v"(x)); return r;
}

// tid0 spins with RELAXED agent loads, then ONE acquire load for the
// synchronizes-with edge. Deadline-bounded (broken protocol -> wrong answer
// + finite time, never a hang). Only 4 lstm blocks ever poll -> no L2 storm.
__device__ inline void wait_flag(int* f, int tgt, int tid, long deadline) {
  if (tid == 0) {
    if (__hip_atomic_load(f, __ATOMIC_RELAXED, __HIP_MEMORY_SCOPE_AGENT) < tgt) {
      while (__hip_atomic_load(f, __ATOMIC_RELAXED, __HIP_MEMORY_SCOPE_AGENT) < tgt) {
        __builtin_amdgcn_s_sleep(32);
        if ((long)__builtin_amdgcn_s_memrealtime() > deadline) break;
      }
    }
    (void)__hip_atomic_load(f, __ATOMIC_ACQUIRE, __HIP_MEMORY_SCOPE_AGENT);
  }
  __syncthreads();
}

// ---------------------------------------------------------------------------
// front_kernel round 24 = EXACT R3 front (943us proven): lstm blocks 0-3 +
// xg 4-515 chunk-major + rbf 516-1027, xgprog flag protocol. qbfT DELETED --
// R10 post-mortem: the transposed store is a 64-lane scatter (4KB-apart
// addresses) = 64 L2 transactions per store per wave per step -> +210us on
// the serial chain. The back kernel proved V-staging-insensitive anyway.
// ---------------------------------------------------------------------------
__global__ __launch_bounds__(512, 2) void front_kernel(
    const float* __restrict__ x, const float* __restrict__ prot,
    const float* __restrict__ W_ih, const float* __restrict__ W_hh,
    const float* __restrict__ b_ih, const float* __restrict__ b_hh,
    _Float16* __restrict__ xg, unsigned short* __restrict__ qbf,
    float* __restrict__ kf, int* __restrict__ prog) {
  // >160KiB/2: exactly 1 block/CU everywhere (isolates lstm CUs).
  __shared__ __align__(16) char smem[82048];
  int tid = threadIdx.x;
  int blk = blockIdx.x;
  long deadline = (long)__builtin_amdgcn_s_memrealtime() + 4000000L;

  if (blk < 4) {
    // ------------------------- LSTM scan -------------------------
    _Float16 (*hbuf)[4 * 144] = (_Float16 (*)[4 * 144])smem;
    int w = tid >> 6, lane = tid & 63;
    int n16 = lane & 15;
    int q8 = lane >> 4;
    int ab = n16 >> 2;
    int u = (w << 4) | n16;
    int bb = blk * 4;
    f16x8 Wf[4][4];
    #pragma unroll
    for (int ty = 0; ty < 4; ++ty) {
      float gs = (ty == 2) ? (2.f * L2E) : (-L2E);
      #pragma unroll
      for (int kb = 0; kb < 4; ++kb) {
        const float* src = &W_hh[(ty * 128 + u) * H_ + kb * 32 + q8 * 8];
        f16x8 v;
        #pragma unroll
        for (int j = 0; j < 8; ++j) v[j] = (_Float16)(src[j] * gs);
        Wf[ty][kb] = v;
      }
    }
    for (int i = tid; i < 2 * 4 * 144; i += 512)
      ((_Float16*)hbuf)[i] = (_Float16)0.f;
    float c = 0.f;
    int hoff = ab * 144 + q8 * 8;
    const _Float16* h0 = &hbuf[0][hoff];
    const _Float16* h1 = &hbuf[1][hoff];
    _Float16* hw = &hbuf[0][q8 * 144 + u];
    const int hstride = 4 * 144;
    const _Float16* xb = xg + (long)(bb + q8) * S_ * G_ + u * 4;
    unsigned short* qp = qbf + (long)(bb + q8) * S_ * H_ + u - H_;
    const _Float16* xpf = xb + 4 * G_;
    // wait for xg chunks 0,1 (covers preload + first group's prefetch)
    wait_flag(&prog[0], 16, tid, deadline);
    wait_flag(&prog[1], 16, tid, deadline);
    f16x4 cur[4];
    #pragma unroll
    for (int p = 0; p < 4; ++p) cur[p] = *(const f16x4*)(xb + (long)p * G_);
    unsigned short hvp = 0;
    __syncthreads();
    for (int t = 0; t < S_; t += 4) {
      if ((t & 63) == 0 && t != 0 && t < 1984)
        wait_flag(&prog[(t >> 6) + 1], 16, tid, deadline);
      #pragma unroll
      for (int p = 0; p < 4; ++p) {
        BAR_LDS();
        const _Float16* hsrc = (p & 1) ? h0 : h1;
        f16x8 A[4];
        #pragma unroll
        for (int kb = 0; kb < 4; ++kb)
          A[kb] = *(const f16x8*)(hsrc + kb * 32);
        if (t + p > 0)
          *qp = hvp;
        qp += H_;
        f16x4 xcur = cur[p];
        cur[p] = *(const f16x4*)xpf;
        xpf += G_;
        f32x4 r0a[4], r1a[4];
        #pragma unroll
        for (int ty = 0; ty < 4; ++ty) {
          f32x4 a0, a1;
          a0[0] = (float)xcur[ty]; a0[1] = 0.f; a0[2] = 0.f; a0[3] = 0.f;
          a1[0] = 0.f; a1[1] = 0.f; a1[2] = 0.f; a1[3] = 0.f;
          a0 = __builtin_amdgcn_mfma_f32_16x16x32_f16(A[0], Wf[ty][0], a0, 0, 0, 0);
          a1 = __builtin_amdgcn_mfma_f32_16x16x32_f16(A[2], Wf[ty][2], a1, 0, 0, 0);
          a0 = __builtin_amdgcn_mfma_f32_16x16x32_f16(A[1], Wf[ty][1], a0, 0, 0, 0);
          a1 = __builtin_amdgcn_mfma_f32_16x16x32_f16(A[3], Wf[ty][3], a1, 0, 0, 0);
          r0a[ty] = a0; r1a[ty] = a1;
        }
        float g0 = r0a[0][0] + r1a[0][0];
        float g1 = r0a[1][0] + r1a[1][0];
        float g2 = r0a[2][0] + r1a[2][0];
        float g3 = r0a[3][0] + r1a[3][0];
        // pre-scaled: g0,g1,g3 by -log2e; g2 by 2log2e
        float ai = rcp_(1.f + exp2_(g0));
        float af = rcp_(1.f + exp2_(g1));
        float ag = 1.f - 2.f * rcp_(1.f + exp2_(g2));
        float ao = rcp_(1.f + exp2_(g3));
        c = af * c + ai * ag;
        float th = 1.f - 2.f * rcp_(1.f + exp2_(c * (2.f * L2E)));
        float hv = ao * th;
        _Float16 hf = (_Float16)hv;
        hw[(p & 1) * hstride] = hf;
        hvp = h2bits(hf);
      }
    }
    *qp = hvp;

  } else if (blk < 516) {
    // ------------------------- xg GEMM -------------------------
    _Float16 (*xs)[136] = (_Float16 (*)[136])smem;             // 64x136
    _Float16 (*ws)[136] = (_Float16 (*)[136])(smem + 17408);   // 128x136
    float* bsum = (float*)(smem + 17408 + 34816);              // 512 f32
    int xblk = blk - 4;
    int batch = xblk & 15, chunk = xblk >> 4;                  // chunk-major
    long R0 = (long)batch * S_ + chunk * 64;
    int lane = tid & 63, w = tid >> 6;
    int tw = w & 3, hi = w >> 2;
    int l15 = lane & 15, q = lane >> 4;
    for (int it = 0; it < 4; ++it) {
      int i = tid + it * 512;          // 2048 = 64 rows * 32 quads
      int r = i >> 5, cx = (i & 31) * 4;
      f32x4a4 v = *(const f32x4a4*)&x[(R0 + r) * 129 + cx];
      f16x4 hq;
      #pragma unroll
      for (int j = 0; j < 4; ++j) hq[j] = (_Float16)v[j];
      *(f16x4*)&xs[r][cx] = hq;
    }
    if (tid < 64) xs[tid][128] = (_Float16)x[(R0 + tid) * 129 + 128];
    bsum[tid] = b_ih[tid] + b_hh[tid];
    __syncthreads();
    f16x8 Bf[4];
    #pragma unroll
    for (int kb = 0; kb < 4; ++kb)
      Bf[kb] = *(const f16x8*)&xs[16 * tw + l15][kb * 32 + q * 8];
    float x128 = (float)xs[16 * tw + l15][128];
    f16x4 res[16];                     // [t*4+r], element = gate chunk
    #pragma unroll
    for (int cg = 0; cg < 4; ++cg) {
      __syncthreads();                 // prior chunk's A-reads done
      for (int it = 0; it < 8; ++it) {
        int i = tid + it * 512;        // 4096 = 128 rows * 32 quads
        int r = i >> 5, cc = (i & 31) * 4;
        f32x4a4 v = *(const f32x4a4*)&W_ih[(long)(cg * 128 + r) * 129 + cc];
        f16x4 hq;
        #pragma unroll
        for (int j = 0; j < 4; ++j) hq[j] = (_Float16)v[j];
        *(f16x4*)&ws[r][cc] = hq;
      }
      if (tid < 128) ws[tid][128] = (_Float16)W_ih[(long)(cg * 128 + tid) * 129 + 128];
      __syncthreads();
      float gs = (cg == 2) ? (2.f * L2E) : (-L2E);
      #pragma unroll
      for (int t = 0; t < 4; ++t) {    // waves split t-tiles: hi*4+t
        int tt = hi * 4 + t;
        f32x4 acc;
        acc[0] = 0.f; acc[1] = 0.f; acc[2] = 0.f; acc[3] = 0.f;
        #pragma unroll
        for (int kb = 0; kb < 4; ++kb) {
          f16x8 Af = *(const f16x8*)&ws[tt * 16 + l15][kb * 32 + q * 8];
          acc = __builtin_amdgcn_mfma_f32_16x16x32_f16(Af, Bf[kb], acc, 0, 0, 0);
        }
        #pragma unroll
        for (int r = 0; r < 4; ++r) {
          int unit = tt * 16 + q * 4 + r;
          float vv = (acc[r] + bsum[cg * 128 + unit] + x128 * (float)ws[unit][128]) * gs;
          res[t * 4 + r][cg] = (_Float16)vv;
        }
      }
    }
    long rowbase = (R0 + 16 * tw + l15) * G_;
    #pragma unroll
    for (int t = 0; t < 4; ++t)
      #pragma unroll
      for (int r = 0; r < 4; ++r)
        *(f16x4*)&xg[rowbase + ((hi * 4 + t) * 16 + q * 4 + r) * 4] = res[t * 4 + r];
    __syncthreads();                   // drains each wave's vmcnt before barrier
    if (tid == 0) {
      __threadfence();
      __hip_atomic_fetch_add(&prog[chunk], 1, __ATOMIC_RELEASE, __HIP_MEMORY_SCOPE_AGENT);
    }

  } else {
    // ------------------------- RBF -------------------------
    int rblk = blk - 516;
    int wave = tid >> 6, lane = tid & 63;
    for (int it = 0; it < 8; ++it) {
      long row = (long)rblk * 64 + it * 8 + wave;
      const float* xr = x + row * F_;
      const float* pr = prot + row * F_;
      float ss = 0.f;
      for (int k = lane; k < F_; k += 64) { float d = xr[k] - pr[k]; ss += d * d; }
      #pragma unroll
      for (int off = 32; off; off >>= 1) ss += __shfl_xor(ss, off, 64);
      if (lane == 0) kf[row] = __expf(-ss);
    }
  }
}

// ---------------------------------------------------------------------------
// back_kernel round 24 = R3's proven back (attn+mlp fused) + two latency
// fixes targeting the diagnosed bottleneck (R10: V-staging-insensitive, ~4x
// above compute floor -> latency-bound at 2 blocks/CU, 3 barriers/chunk):
//  (1) T14 async-STAGE: chunk t+1's K/V rows preloaded into 4xs16x8 regs
//      right after chunk t's LDS stage-write; ~3us of compute hides the
//      global latency. Same loads, same math -> bit-identical output.
//  (2) T5 s_setprio(1) around QK and PV MFMA clusters (2 independent
//      blocks/CU -> scheduler has wave-role diversity to exploit).
// ---------------------------------------------------------------------------
__global__ __launch_bounds__(256) void back_kernel(
    const unsigned short* __restrict__ qbf, const float* __restrict__ kf,
    const float* __restrict__ Wc, const float* __restrict__ bc,
    const float* __restrict__ Wh, const float* __restrict__ bh,
    float* __restrict__ out) {
  __shared__ __align__(16) char smem[74560];
  _Float16 (*hb)[64][136] = (_Float16 (*)[64][136])smem;            // 2x17408
  unsigned short* Ps = (unsigned short*)(smem + 17408);             // in hb[1]
  unsigned short* Ks = (unsigned short*)(smem + 34816);             // 17408
  unsigned short* VT = (unsigned short*)(smem + 34816 + 17408);     // 18432
  _Float16 (*wl)[136] = (_Float16 (*)[136])(smem + 34816);         // 39168
  float* bl = (float*)(smem + 34816 + 39168);                       // 576

  int tid = threadIdx.x;
  int lane = tid & 63, w = tid >> 6;
  int b = blockIdx.x >> 5;
  int q0 = (blockIdx.x & 31) * 64;
  long R0 = (long)blockIdx.x * 64;     // == b*S + q0
  const unsigned short* qb = qbf + (long)b * S_ * H_;
  int l15 = lane & 15;
  int q = lane >> 4;
  int koff = q * 8;

  // ---- attention phase ----
  f16x8 qfrag[4];
  #pragma unroll
  for (int kb = 0; kb < 4; ++kb)
    qfrag[kb] = *(const f16x8*)(qb + (long)(q0 + w * 16 + l15) * H_ + kb * 32 + koff);
  f32x4 oacc[8];
  #pragma unroll
  for (int n = 0; n < 8; ++n)
    #pragma unroll
    for (int r = 0; r < 4; ++r) oacc[n][r] = 0.f;
  float mrow[4], lrow[4];
  #pragma unroll
  for (int r = 0; r < 4; ++r) { mrow[r] = -1e30f; lrow[r] = 0.f; }
  const float scale = 0.08804509063256238f;  // 1/sqrt(129)
  unsigned short* Pw = Ps + w * 16 * 72;
  int rr = tid >> 4;
  int c0 = (tid & 15) * 8;
  // T14: preload chunk 0's K/V rows into registers
  s16x8 vstage[4];
  #pragma unroll
  for (int pch = 0; pch < 4; ++pch)
    vstage[pch] = *(const s16x8*)(qb + (long)(pch * 16 + rr) * H_ + c0);
  for (int t = 0; t < S_ / 64; ++t) {
    {
      // stage-write from registers (K row-major + V transposed/swizzled)
      #pragma unroll
      for (int pch = 0; pch < 4; ++pch) {
        int r = pch * 16 + rr;
        s16x8 v = vstage[pch];
        *(s16x8*)(&Ks[r * 136 + c0]) = v;
        int rbase = r >> 3, rl = r & 7;
        #pragma unroll
        for (int i = 0; i < 8; ++i) {
          int d = c0 + i;
          VT[d * 72 + ((rbase ^ ((d >> 3) & 7)) << 3) + rl] = (unsigned short)v[i];
        }
      }
      // T14: issue next chunk's loads (complete during this chunk's compute)
      if (t + 1 < S_ / 64) {
        #pragma unroll
        for (int pch = 0; pch < 4; ++pch)
          vstage[pch] = *(const s16x8*)(qb + (long)((t + 1) * 64 + pch * 16 + rr) * H_ + c0);
      }
    }
    __syncthreads();
    f32x4 sacc[4];
    __builtin_amdgcn_s_setprio(1);
    #pragma unroll
    for (int n = 0; n < 4; ++n) {
      f32x4 acc;
      #pragma unroll
      for (int r = 0; r < 4; ++r) acc[r] = 0.f;
      #pragma unroll
      for (int kb = 0; kb < 4; ++kb) {
        f16x8 bfrag = *(const f16x8*)(&Ks[(n * 16 + l15) * 136 + kb * 32 + koff]);
        acc = __builtin_amdgcn_mfma_f32_16x16x32_f16(qfrag[kb], bfrag, acc, 0, 0, 0);
      }
      sacc[n] = acc;
    }
    __builtin_amdgcn_s_setprio(0);
    #pragma unroll
    for (int r = 0; r < 4; ++r) {
      float mx = fmaxf(fmaxf(sacc[0][r], sacc[1][r]), fmaxf(sacc[2][r], sacc[3][r]));
      #pragma unroll
      for (int m = 1; m < 16; m <<= 1) mx = fmaxf(mx, __shfl_xor(mx, m, 64));
      mx *= scale;
      float mnew = fmaxf(mrow[r], mx);
      float alpha = __expf(mrow[r] - mnew);
      mrow[r] = mnew;
      float psum = 0.f;
      #pragma unroll
      for (int n = 0; n < 4; ++n) {
        float pv = __expf(sacc[n][r] * scale - mnew);
        sacc[n][r] = pv;
        psum += pv;
      }
      #pragma unroll
      for (int m = 1; m < 16; m <<= 1) psum += __shfl_xor(psum, m, 64);
      lrow[r] = lrow[r] * alpha + psum;
      #pragma unroll
      for (int n = 0; n < 8; ++n) oacc[n][r] *= alpha;
    }
    #pragma unroll
    for (int n = 0; n < 4; ++n)
      #pragma unroll
      for (int r = 0; r < 4; ++r)
        Pw[(q * 4 + r) * 72 + n * 16 + l15] = f2h(sacc[n][r]);
    __syncthreads();
    __builtin_amdgcn_s_setprio(1);
    #pragma unroll
    for (int kb = 0; kb < 2; ++kb) {
      f16x8 afrag = *(const f16x8*)(&Pw[l15 * 72 + kb * 32 + koff]);
      #pragma unroll
      for (int n = 0; n < 8; ++n) {
        int d = n * 16 + l15;
        int rb = ((kb * 32 + koff) >> 3) ^ ((d >> 3) & 7);
        f16x8 bfrag = *(const f16x8*)(&VT[d * 72 + (rb << 3)]);
        oacc[n] = __builtin_amdgcn_mfma_f32_16x16x32_f16(afrag, bfrag, oacc[n], 0, 0, 0);
      }
    }
    __builtin_amdgcn_s_setprio(0);
    __syncthreads();
  }
  // ---- epilogue: oacc -> hb[0] (f16), kf -> col 128 ----
  float rl4[4];
  #pragma unroll
  for (int r = 0; r < 4; ++r) rl4[r] = rcp_(lrow[r]);
  #pragma unroll
  for (int n = 0; n < 8; ++n)
    #pragma unroll
    for (int r = 0; r < 4; ++r)
      hb[0][w * 16 + q * 4 + r][n * 16 + l15] = (_Float16)(oacc[n][r] * rl4[r]);
  if (tid < 64) hb[0][tid][128] = (_Float16)kf[R0 + tid];

  // ---- MLP phase ----
  int cur = 0;
  for (int l = 0; l < 4; ++l) {
    __syncthreads();                 // h writes + prior wl reads done
    for (int it = 0; it < 18; ++it) {
      int i = tid + it * 256;        // 4608 = 144 rows * 32 quads
      int r = i >> 5, cc = (i & 31) * 4;
      int rs = (r < 129) ? r : 128;  // dup row 128 into pad rows (garbage-safe)
      f32x4a4 v = *(const f32x4a4*)&Wc[((long)l * 129 + rs) * 129 + cc];
      f16x4 hq;
      #pragma unroll
      for (int j = 0; j < 4; ++j) hq[j] = (_Float16)v[j];
      *(f16x4*)&wl[r][cc] = hq;
    }
    if (tid < 144) {
      int rs = (tid < 129) ? tid : 128;
      wl[tid][128] = (_Float16)Wc[((long)l * 129 + rs) * 129 + 128];
      bl[tid] = bc[l * 129 + rs];
    }
    __syncthreads();
    f16x8 Bf[4];
    #pragma unroll
    for (int kb = 0; kb < 4; ++kb)
      Bf[kb] = *(const f16x8*)&hb[cur][16 * w + l15][kb * 32 + q * 8];
    float h128 = (float)hb[cur][16 * w + l15][128];
    int nxt = cur ^ 1;
    #pragma unroll
    for (int t = 0; t < 9; ++t) {
      f32x4 acc;
      acc[0] = 0.f; acc[1] = 0.f; acc[2] = 0.f; acc[3] = 0.f;
      #pragma unroll
      for (int kb = 0; kb < 4; ++kb) {
        f16x8 Af = *(const f16x8*)&wl[t * 16 + l15][kb * 32 + q * 8];
        acc = __builtin_amdgcn_mfma_f32_16x16x32_f16(Af, Bf[kb], acc, 0, 0, 0);
      }
      f16x4 hv;
      #pragma unroll
      for (int r = 0; r < 4; ++r) {
        int u = t * 16 + q * 4 + r;
        float v = acc[r] + bl[u] + h128 * (float)wl[u][128];
        hv[r] = (_Float16)fmaxf(v, 0.f);
      }
      if (t < 8)
        *(f16x4*)&hb[nxt][16 * w + l15][t * 16 + q * 4] = hv;
      else if (q == 0)
        hb[nxt][16 * w + l15][128] = hv[0];   // only unit 128 is real
    }
    cur ^= 1;
  }
  __syncthreads();
  if (tid < 128) {
    int row = tid >> 1, j = tid & 1;
    float z = bh[j];
    const float* whp = Wh + j * 129;
    for (int k = 0; k < 129; ++k) z += (float)hb[cur][row][k] * whp[k];
    float zo = __shfl_xor(z, 1, 64);   // partner lane: same row, other class
    float mx = fmaxf(z, zo);
    float lse = mx + __logf(__expf(z - mx) + __expf(zo - mx));
    out[(R0 + row) * 2 + j] = z - lse;
  }
}

extern "C" void kernel_launch(void* const* d_in, const int* in_sizes, int n_in,
                              void* d_out, int out_size, void* d_ws, size_t ws_size,
                              hipStream_t stream) {
  const float* x    = (const float*)d_in[0];
  const float* prot = (const float*)d_in[1];
  const float* W_ih = (const float*)d_in[2];
  const float* W_hh = (const float*)d_in[3];
  const float* b_ih = (const float*)d_in[4];
  const float* b_hh = (const float*)d_in[5];
  const float* Wc   = (const float*)d_in[6];
  const float* bc   = (const float*)d_in[7];
  const float* Wh   = (const float*)d_in[8];
  const float* bh   = (const float*)d_in[9];
  float* out = (float*)d_out;
  char* ws = (char*)d_ws;
  _Float16* xgh       = (_Float16*)(ws);                      // 33554432 B
  unsigned short* qbf = (unsigned short*)(ws + 33554432);     //  8388608 B (f16 bits)
  float* kf           = (float*)(ws + 41943040);              //   131072 B
  int* prog           = (int*)(ws + 42074112);                //      128 B

  hipMemsetAsync(prog, 0, 128, stream);
  hipLaunchKernelGGL(front_kernel, dim3(1028), dim3(512), 0, stream,
                     x, prot, W_ih, W_hh, b_ih, b_hh, xgh, qbf, kf, prog);
  hipLaunchKernelGGL(back_kernel, dim3(512), dim3(256), 0, stream,
                     qbf, kf, Wc, bc, Wh, bh, out);
}